// Round 10
// baseline (79.007 us; speedup 1.0000x reference)
//
#include <hip/hip_runtime.h>

typedef float v2f __attribute__((ext_vector_type(2)));
typedef float v4f __attribute__((ext_vector_type(4)));

#define IMG_H 384
#define IMG_W 512
#define RPT 8           // output rows per thread
#define TY  2           // strips per block
#define NLX 128         // lanes across x (128 * 4 cols = 512)

struct Raw  { v4f p, t; float pe, te; };
struct RowH { v2f hx[4]; v2f hxx[4]; float hpt[4]; };

__device__ __forceinline__ int reflect_y(int gy) {
    if (gy < 0) gy = -gy;
    else if (gy >= IMG_H) gy = 2 * IMG_H - 2 - gy;
    return gy;
}

// ---------------- ablation: exact memory skeleton, no SSIM math ----------------
__global__ __launch_bounds__(NLX * TY) void ssim_mem_skeleton(
    const float* __restrict__ pred,
    const float* __restrict__ target,
    float* __restrict__ out)
{
    const int lx   = threadIdx.x;
    const int lane = lx & 63;
    const int col0 = 4 * lx;
    const size_t base = (size_t)blockIdx.z * (IMG_H * IMG_W);
    const int y0 = (blockIdx.y * TY + threadIdx.y) * RPT;

    const bool needL = (lane == 0)  && (col0 != 0);
    const bool needR = (lane == 63) && (col0 + 4 != IMG_W);
    const int  eoff  = needL ? (col0 - 1) : (needR ? (col0 + 4) : col0);

    v4f acc = {0.f, 0.f, 0.f, 0.f};
    float acce = 0.f;
    #pragma unroll
    for (int k = 0; k < RPT + 2; ++k) {
        int gy = reflect_y(y0 - 1 + k);
        const float* rp = pred   + base + (size_t)gy * IMG_W;
        const float* rt = target + base + (size_t)gy * IMG_W;
        v4f p = *(const v4f*)(rp + col0);
        v4f t = *(const v4f*)(rt + col0);
        float pe = rp[eoff], te = rt[eoff];
        acc += p + t;
        acce += pe + te;
    }
    v4f sv = acc + acce;   // keeps every load live
    #pragma unroll
    for (int r = 0; r < RPT; ++r)
        __builtin_nontemporal_store(sv, (v4f*)(out + base + (size_t)(y0 + r) * IMG_W + col0));
}

// ---------------- real kernel (R9, unchanged) ----------------
#define ISSUE(S, RY) do {                                                          \
    int gy_ = reflect_y(RY);                                                       \
    const float* rp_ = pred   + base + (size_t)gy_ * IMG_W;                        \
    const float* rt_ = target + base + (size_t)gy_ * IMG_W;                        \
    asm volatile("global_load_dwordx4 %0, %1, off" : "=v"(raw##S.p)  : "v"(rp_ + col0)); \
    asm volatile("global_load_dwordx4 %0, %1, off" : "=v"(raw##S.t)  : "v"(rt_ + col0)); \
    asm volatile("global_load_dword %0, %1, off"   : "=v"(raw##S.pe) : "v"(rp_ + eoff)); \
    asm volatile("global_load_dword %0, %1, off"   : "=v"(raw##S.te) : "v"(rt_ + eoff)); \
} while (0)

#define WAITV(N) do {                                                              \
    asm volatile("s_waitcnt vmcnt(" #N ")" ::: "memory");                          \
    __builtin_amdgcn_sched_barrier(0);                                             \
} while (0)

__device__ __forceinline__ RowH reduce_row(const Raw& r, int lane, int col0)
{
    float x0p = __shfl_up(r.p.w, 1);
    float x0t = __shfl_up(r.t.w, 1);
    float x5p = __shfl_down(r.p.x, 1);
    float x5t = __shfl_down(r.t.x, 1);
    if (lane == 0) {
        if (col0 == 0) { x0p = r.p.y; x0t = r.t.y; }
        else           { x0p = r.pe;  x0t = r.te;  }
    }
    if (lane == 63) {
        if (col0 + 4 == IMG_W) { x5p = r.p.z; x5t = r.t.z; }
        else                   { x5p = r.pe;  x5t = r.te;  }
    }

    v2f x0 = {x0p,   x0t};
    v2f x1 = {r.p.x, r.t.x};
    v2f x2 = {r.p.y, r.t.y};
    v2f x3 = {r.p.z, r.t.z};
    v2f x4 = {r.p.w, r.t.w};
    v2f x5 = {x5p,   x5t};

    RowH h;
    v2f a = x1 + x2, b = x3 + x4;
    h.hx[0] = x0 + a;  h.hx[1] = a + x3;
    h.hx[2] = x2 + b;  h.hx[3] = b + x5;

    v2f q0 = x0*x0, q1 = x1*x1, q2 = x2*x2, q3 = x3*x3, q4 = x4*x4, q5 = x5*x5;
    v2f aq = q1 + q2, bq = q3 + q4;
    h.hxx[0] = q0 + aq;  h.hxx[1] = aq + q3;
    h.hxx[2] = q2 + bq;  h.hxx[3] = bq + q5;

    float m0 = x0.x*x0.y, m1 = x1.x*x1.y, m2 = x2.x*x2.y,
          m3 = x3.x*x3.y, m4 = x4.x*x4.y, m5 = x5.x*x5.y;
    float am = m1 + m2, bm = m3 + m4;
    h.hpt[0] = m0 + am;  h.hpt[1] = am + m3;
    h.hpt[2] = m2 + bm;  h.hpt[3] = bm + m5;
    return h;
}

__device__ __forceinline__ void emit_row(
    float* __restrict__ out, size_t base, int row, int col0,
    const RowH& A, const RowH& B, const RowH& C)
{
    const float C1 = 1e-4f;
    const float C2 = 9e-4f;
    const float inv9 = 1.0f / 9.0f;

    v4f rv;
    #pragma unroll
    for (int j = 0; j < 4; ++j) {
        v2f sx  = A.hx[j]  + B.hx[j]  + C.hx[j];
        v2f sxx = A.hxx[j] + B.hxx[j] + C.hxx[j];
        float spt = A.hpt[j] + B.hpt[j] + C.hpt[j];

        v2f u  = sx * inv9;
        v2f uu = u * u;
        v2f sig = sxx * inv9 - uu;
        float upt   = u.x * u.y;
        float sigco = fmaf(spt, inv9, -upt);

        float num = fmaf(2.f, upt, C1) * fmaf(2.f, sigco, C2);
        float den = (uu.x + uu.y + C1) * (sig.x + sig.y + C2);
        float q = num * __builtin_amdgcn_rcpf(den);
        rv[j] = fminf(fmaxf(fmaf(q, -0.5f, 0.5f), 0.f), 1.f);
    }
    __builtin_nontemporal_store(rv, (v4f*)(out + base + (size_t)row * IMG_W + col0));
}

__global__ __launch_bounds__(NLX * TY) void ssim_kernel(
    const float* __restrict__ pred,
    const float* __restrict__ target,
    float* __restrict__ out)
{
    const int lx   = threadIdx.x;
    const int lane = lx & 63;
    const int col0 = 4 * lx;
    const size_t base = (size_t)blockIdx.z * (IMG_H * IMG_W);
    const int y0 = (blockIdx.y * TY + threadIdx.y) * RPT;

    const bool needL = (lane == 0)  && (col0 != 0);
    const bool needR = (lane == 63) && (col0 + 4 != IMG_W);
    const int  eoff  = needL ? (col0 - 1) : (needR ? (col0 + 4) : col0);

    Raw raw0, raw1, raw2, raw3;
    RowH h0, h1, h2;

    ISSUE(0, y0 - 1); ISSUE(1, y0); ISSUE(2, y0 + 1); ISSUE(3, y0 + 2);
    WAITV(12); h0 = reduce_row(raw0, lane, col0);
    WAITV(8);  h1 = reduce_row(raw1, lane, col0);

    ISSUE(0, y0 + 3); WAITV(8); h2 = reduce_row(raw2, lane, col0);
    emit_row(out, base, y0 + 0, col0, h0, h1, h2);
    ISSUE(1, y0 + 4); WAITV(8); h0 = reduce_row(raw3, lane, col0);
    emit_row(out, base, y0 + 1, col0, h1, h2, h0);
    ISSUE(2, y0 + 5); WAITV(8); h1 = reduce_row(raw0, lane, col0);
    emit_row(out, base, y0 + 2, col0, h2, h0, h1);
    ISSUE(3, y0 + 6); WAITV(8); h2 = reduce_row(raw1, lane, col0);
    emit_row(out, base, y0 + 3, col0, h0, h1, h2);
    ISSUE(0, y0 + 7); WAITV(8); h0 = reduce_row(raw2, lane, col0);
    emit_row(out, base, y0 + 4, col0, h1, h2, h0);
    ISSUE(1, y0 + 8); WAITV(8); h1 = reduce_row(raw3, lane, col0);
    emit_row(out, base, y0 + 5, col0, h2, h0, h1);
                      WAITV(4); h2 = reduce_row(raw0, lane, col0);
    emit_row(out, base, y0 + 6, col0, h0, h1, h2);
                      WAITV(0); h0 = reduce_row(raw1, lane, col0);
    emit_row(out, base, y0 + 7, col0, h1, h2, h0);
}

extern "C" void kernel_launch(void* const* d_in, const int* in_sizes, int n_in,
                              void* d_out, int out_size, void* d_ws, size_t ws_size,
                              hipStream_t stream) {
    const float* pred   = (const float*)d_in[0];
    const float* target = (const float*)d_in[1];
    float* out = (float*)d_out;

    const int planes = in_sizes[0] / (IMG_H * IMG_W);   // 32*3 = 96

    dim3 block(NLX, TY);                                 // 256 threads
    dim3 grid(1, IMG_H / (TY * RPT), planes);            // (1, 24, 96)

    // Dispatch 1: memory-skeleton ablation (writes scratch values to d_out).
    ssim_mem_skeleton<<<grid, block, 0, stream>>>(pred, target, out);
    // Dispatch 2: real kernel, runs last -> d_out is fully correct.
    ssim_kernel<<<grid, block, 0, stream>>>(pred, target, out);
}

// Round 11
// 52.079 us; speedup vs baseline: 1.5171x; 1.5171x over previous
//
#include <hip/hip_runtime.h>

typedef float v2f __attribute__((ext_vector_type(2)));
typedef float v4f __attribute__((ext_vector_type(4)));

#define IMG_H 384
#define IMG_W 512
#define RPT 8           // output rows per wave-strip
#define TY  2           // wave-strips per block (block = 64 x TY)

struct Raw8 { v4f pa, pb, ta, tb; };                    // lane's cols 8l..8l+7, both arrays
struct H8   { v2f hx[8]; v2f hxx[8]; float hpt[8]; };   // horizontal 3-tap sums, 8 outputs

__device__ __forceinline__ int reflect_y(int gy) {
    if (gy < 0) gy = -gy;
    else if (gy >= IMG_H) gy = 2 * IMG_H - 2 - gy;
    return gy;
}

// Issue one row's 4 fat loads into ring slot S. Volatile: cannot be sunk/collapsed.
#define ISSUE(S, RY) do {                                                                 \
    int gy_ = reflect_y(RY);                                                              \
    const float* rp_ = pred   + base + (size_t)gy_ * IMG_W + col0;                        \
    const float* rt_ = target + base + (size_t)gy_ * IMG_W + col0;                        \
    asm volatile("global_load_dwordx4 %0, %1, off" : "=v"(S.pa) : "v"(rp_));              \
    asm volatile("global_load_dwordx4 %0, %1, off" : "=v"(S.pb) : "v"(rp_ + 4));          \
    asm volatile("global_load_dwordx4 %0, %1, off" : "=v"(S.ta) : "v"(rt_));              \
    asm volatile("global_load_dwordx4 %0, %1, off" : "=v"(S.tb) : "v"(rt_ + 4));          \
} while (0)

// Counted wait + scheduling fence (rule #18: fence AFTER the waitcnt).
#define WAITV(N) do {                                                                     \
    asm volatile("s_waitcnt vmcnt(" #N ")" ::: "memory");                                 \
    __builtin_amdgcn_sched_barrier(0);                                                    \
} while (0)

__device__ __forceinline__ H8 hrow(const Raw8& r, int lane)
{
    // window cols 8l-1 .. 8l+8; the two edges come from neighbor lanes in the SAME wave
    float xm1p = __shfl_up(r.pb.w, 1);
    float xm1t = __shfl_up(r.tb.w, 1);
    float xp8p = __shfl_down(r.pa.x, 1);
    float xp8t = __shfl_down(r.ta.x, 1);
    if (lane == 0)  { xm1p = r.pa.y; xm1t = r.ta.y; }   // reflect col -1 -> 1
    if (lane == 63) { xp8p = r.pb.z; xp8t = r.tb.z; }   // reflect col 512 -> 510

    v2f x0 = {xm1p,   xm1t};
    v2f x1 = {r.pa.x, r.ta.x};
    v2f x2 = {r.pa.y, r.ta.y};
    v2f x3 = {r.pa.z, r.ta.z};
    v2f x4 = {r.pa.w, r.ta.w};
    v2f x5 = {r.pb.x, r.tb.x};
    v2f x6 = {r.pb.y, r.tb.y};
    v2f x7 = {r.pb.z, r.tb.z};
    v2f x8 = {r.pb.w, r.tb.w};
    v2f x9 = {xp8p,   xp8t};

    H8 h;
    {   // hx[c] = x[c]+x[c+1]+x[c+2], shared pair sums
        v2f p12 = x1 + x2, p34 = x3 + x4, p56 = x5 + x6, p78 = x7 + x8;
        h.hx[0] = x0 + p12;  h.hx[1] = p12 + x3;
        h.hx[2] = x2 + p34;  h.hx[3] = p34 + x5;
        h.hx[4] = x4 + p56;  h.hx[5] = p56 + x7;
        h.hx[6] = x6 + p78;  h.hx[7] = p78 + x9;
    }
    {   // squares
        v2f q0 = x0*x0, q1 = x1*x1, q2 = x2*x2, q3 = x3*x3, q4 = x4*x4,
            q5 = x5*x5, q6 = x6*x6, q7 = x7*x7, q8 = x8*x8, q9 = x9*x9;
        v2f p12 = q1 + q2, p34 = q3 + q4, p56 = q5 + q6, p78 = q7 + q8;
        h.hxx[0] = q0 + p12;  h.hxx[1] = p12 + q3;
        h.hxx[2] = q2 + p34;  h.hxx[3] = p34 + q5;
        h.hxx[4] = q4 + p56;  h.hxx[5] = p56 + q7;
        h.hxx[6] = q6 + p78;  h.hxx[7] = p78 + q9;
    }
    {   // cross terms
        float m0 = x0.x*x0.y, m1 = x1.x*x1.y, m2 = x2.x*x2.y, m3 = x3.x*x3.y,
              m4 = x4.x*x4.y, m5 = x5.x*x5.y, m6 = x6.x*x6.y, m7 = x7.x*x7.y,
              m8 = x8.x*x8.y, m9 = x9.x*x9.y;
        float p12 = m1 + m2, p34 = m3 + m4, p56 = m5 + m6, p78 = m7 + m8;
        h.hpt[0] = m0 + p12;  h.hpt[1] = p12 + m3;
        h.hpt[2] = m2 + p34;  h.hpt[3] = p34 + m5;
        h.hpt[4] = m4 + p56;  h.hpt[5] = p56 + m7;
        h.hpt[6] = m6 + p78;  h.hpt[7] = p78 + m9;
    }
    return h;
}

__device__ __forceinline__ void emit_row(
    float* __restrict__ out, size_t base, int row, int col0,
    const H8& A, const H8& B, const H8& C)
{
    const float C1 = 1e-4f;    // 0.01^2
    const float C2 = 9e-4f;    // 0.03^2
    const float inv9 = 1.0f / 9.0f;

    v4f lo, hi;
    #pragma unroll
    for (int j = 0; j < 8; ++j) {
        v2f sx  = A.hx[j]  + B.hx[j]  + C.hx[j];
        v2f sxx = A.hxx[j] + B.hxx[j] + C.hxx[j];
        float spt = A.hpt[j] + B.hpt[j] + C.hpt[j];

        v2f u  = sx * inv9;
        v2f uu = u * u;
        v2f sig = sxx * inv9 - uu;
        float upt   = u.x * u.y;
        float sigco = fmaf(spt, inv9, -upt);

        float num = fmaf(2.f, upt, C1) * fmaf(2.f, sigco, C2);
        float den = (uu.x + uu.y + C1) * (sig.x + sig.y + C2);
        float q = num * __builtin_amdgcn_rcpf(den);
        float v = fminf(fmaxf(fmaf(q, -0.5f, 0.5f), 0.f), 1.f);
        if (j < 4) lo[j] = v; else hi[j - 4] = v;
    }
    float* o = out + base + (size_t)row * IMG_W + col0;
    __builtin_nontemporal_store(lo, (v4f*)o);
    __builtin_nontemporal_store(hi, (v4f*)(o + 4));
}

__global__ __launch_bounds__(64 * TY, 2) void ssim_kernel(
    const float* __restrict__ pred,
    const float* __restrict__ target,
    float* __restrict__ out)
{
    const int lane = threadIdx.x;            // 0..63, one wave spans the full width
    const int col0 = 8 * lane;
    const size_t base = (size_t)blockIdx.z * (IMG_H * IMG_W);
    const int y0 = (blockIdx.y * TY + threadIdx.y) * RPT;

    Raw8 ra, rb, rc;
    H8 hA, hB, hC;

    // prologue: rows y0-1, y0, y0+1 (12 loads in flight)
    ISSUE(ra, y0 - 1); ISSUE(rb, y0); ISSUE(rc, y0 + 1);
    WAITV(8); hA = hrow(ra, lane);
    WAITV(4); hB = hrow(rb, lane);

    // steady state: issue row r+2, consume row r+1 (2 rows = 8 fat loads in flight)
    ISSUE(ra, y0 + 2); WAITV(4); hC = hrow(rc, lane);
    emit_row(out, base, y0 + 0, col0, hA, hB, hC);
    ISSUE(rb, y0 + 3); WAITV(4); hA = hrow(ra, lane);
    emit_row(out, base, y0 + 1, col0, hB, hC, hA);
    ISSUE(rc, y0 + 4); WAITV(4); hB = hrow(rb, lane);
    emit_row(out, base, y0 + 2, col0, hC, hA, hB);
    ISSUE(ra, y0 + 5); WAITV(4); hC = hrow(rc, lane);
    emit_row(out, base, y0 + 3, col0, hA, hB, hC);
    ISSUE(rb, y0 + 6); WAITV(4); hA = hrow(ra, lane);
    emit_row(out, base, y0 + 4, col0, hB, hC, hA);
    ISSUE(rc, y0 + 7); WAITV(4); hB = hrow(rb, lane);
    emit_row(out, base, y0 + 5, col0, hC, hA, hB);
    ISSUE(ra, y0 + 8); WAITV(4); hC = hrow(rc, lane);
    emit_row(out, base, y0 + 6, col0, hA, hB, hC);
    /* tail */         WAITV(0); hA = hrow(ra, lane);
    emit_row(out, base, y0 + 7, col0, hB, hC, hA);
}

extern "C" void kernel_launch(void* const* d_in, const int* in_sizes, int n_in,
                              void* d_out, int out_size, void* d_ws, size_t ws_size,
                              hipStream_t stream) {
    const float* pred   = (const float*)d_in[0];
    const float* target = (const float*)d_in[1];
    float* out = (float*)d_out;

    const int planes = in_sizes[0] / (IMG_H * IMG_W);   // 32*3 = 96

    dim3 block(64, TY);                                  // 128 threads = 2 waves
    dim3 grid(1, IMG_H / (TY * RPT), planes);            // (1, 24, 96)
    ssim_kernel<<<grid, block, 0, stream>>>(pred, target, out);
}

// Round 12
// 48.035 us; speedup vs baseline: 1.6448x; 1.0842x over previous
//
#include <hip/hip_runtime.h>

typedef float v2f __attribute__((ext_vector_type(2)));
typedef float v4f __attribute__((ext_vector_type(4)));

#define IMG_H 384
#define IMG_W 512
#define RPT 8           // output rows per wave-strip
#define TY  4           // wave-strips per block (block = 64 x TY = 256 threads)

struct Raw8 { v4f pa, pb, ta, tb; };                    // lane's cols 8l..8l+7, both arrays
struct H8   { v2f hx[8]; v2f hxx[8]; float hpt[8]; };   // horizontal 3-tap sums, 8 outputs

__device__ __forceinline__ int reflect_y(int gy) {
    if (gy < 0) gy = -gy;
    else if (gy >= IMG_H) gy = 2 * IMG_H - 2 - gy;
    return gy;
}

// Issue one row's 4 fat loads into ring slot S. Volatile: cannot be sunk/collapsed.
#define ISSUE(S, RY) do {                                                                 \
    int gy_ = reflect_y(RY);                                                              \
    const float* rp_ = pred   + base + (size_t)gy_ * IMG_W + col0;                        \
    const float* rt_ = target + base + (size_t)gy_ * IMG_W + col0;                        \
    asm volatile("global_load_dwordx4 %0, %1, off" : "=v"(S.pa) : "v"(rp_));              \
    asm volatile("global_load_dwordx4 %0, %1, off" : "=v"(S.pb) : "v"(rp_ + 4));          \
    asm volatile("global_load_dwordx4 %0, %1, off" : "=v"(S.ta) : "v"(rt_));              \
    asm volatile("global_load_dwordx4 %0, %1, off" : "=v"(S.tb) : "v"(rt_ + 4));          \
} while (0)

// Counted wait + scheduling fence (rule #18: fence AFTER the waitcnt).
#define WAITV(N) do {                                                                     \
    asm volatile("s_waitcnt vmcnt(" #N ")" ::: "memory");                                 \
    __builtin_amdgcn_sched_barrier(0);                                                    \
} while (0)

__device__ __forceinline__ H8 hrow(const Raw8& r, int lane)
{
    // window cols 8l-1 .. 8l+8; the two edges come from neighbor lanes in the SAME wave
    float xm1p = __shfl_up(r.pb.w, 1);
    float xm1t = __shfl_up(r.tb.w, 1);
    float xp8p = __shfl_down(r.pa.x, 1);
    float xp8t = __shfl_down(r.ta.x, 1);
    if (lane == 0)  { xm1p = r.pa.y; xm1t = r.ta.y; }   // reflect col -1 -> 1
    if (lane == 63) { xp8p = r.pb.z; xp8t = r.tb.z; }   // reflect col 512 -> 510

    v2f x0 = {xm1p,   xm1t};
    v2f x1 = {r.pa.x, r.ta.x};
    v2f x2 = {r.pa.y, r.ta.y};
    v2f x3 = {r.pa.z, r.ta.z};
    v2f x4 = {r.pa.w, r.ta.w};
    v2f x5 = {r.pb.x, r.tb.x};
    v2f x6 = {r.pb.y, r.tb.y};
    v2f x7 = {r.pb.z, r.tb.z};
    v2f x8 = {r.pb.w, r.tb.w};
    v2f x9 = {xp8p,   xp8t};

    H8 h;
    {   // hx[c] = x[c]+x[c+1]+x[c+2], shared pair sums
        v2f p12 = x1 + x2, p34 = x3 + x4, p56 = x5 + x6, p78 = x7 + x8;
        h.hx[0] = x0 + p12;  h.hx[1] = p12 + x3;
        h.hx[2] = x2 + p34;  h.hx[3] = p34 + x5;
        h.hx[4] = x4 + p56;  h.hx[5] = p56 + x7;
        h.hx[6] = x6 + p78;  h.hx[7] = p78 + x9;
    }
    {   // squares
        v2f q0 = x0*x0, q1 = x1*x1, q2 = x2*x2, q3 = x3*x3, q4 = x4*x4,
            q5 = x5*x5, q6 = x6*x6, q7 = x7*x7, q8 = x8*x8, q9 = x9*x9;
        v2f p12 = q1 + q2, p34 = q3 + q4, p56 = q5 + q6, p78 = q7 + q8;
        h.hxx[0] = q0 + p12;  h.hxx[1] = p12 + q3;
        h.hxx[2] = q2 + p34;  h.hxx[3] = p34 + q5;
        h.hxx[4] = q4 + p56;  h.hxx[5] = p56 + q7;
        h.hxx[6] = q6 + p78;  h.hxx[7] = p78 + q9;
    }
    {   // cross terms
        float m0 = x0.x*x0.y, m1 = x1.x*x1.y, m2 = x2.x*x2.y, m3 = x3.x*x3.y,
              m4 = x4.x*x4.y, m5 = x5.x*x5.y, m6 = x6.x*x6.y, m7 = x7.x*x7.y,
              m8 = x8.x*x8.y, m9 = x9.x*x9.y;
        float p12 = m1 + m2, p34 = m3 + m4, p56 = m5 + m6, p78 = m7 + m8;
        h.hpt[0] = m0 + p12;  h.hpt[1] = p12 + m3;
        h.hpt[2] = m2 + p34;  h.hpt[3] = p34 + m5;
        h.hpt[4] = m4 + p56;  h.hpt[5] = p56 + m7;
        h.hpt[6] = m6 + p78;  h.hpt[7] = p78 + m9;
    }
    return h;
}

__device__ __forceinline__ void emit_row(
    float* __restrict__ out, size_t base, int row, int col0,
    const H8& A, const H8& B, const H8& C)
{
    const float C1 = 1e-4f;    // 0.01^2
    const float C2 = 9e-4f;    // 0.03^2
    const float inv9 = 1.0f / 9.0f;

    v4f lo, hi;
    #pragma unroll
    for (int j = 0; j < 8; ++j) {
        v2f sx  = A.hx[j]  + B.hx[j]  + C.hx[j];
        v2f sxx = A.hxx[j] + B.hxx[j] + C.hxx[j];
        float spt = A.hpt[j] + B.hpt[j] + C.hpt[j];

        v2f u  = sx * inv9;
        v2f uu = u * u;
        v2f sig = sxx * inv9 - uu;
        float upt   = u.x * u.y;
        float sigco = fmaf(spt, inv9, -upt);

        float num = fmaf(2.f, upt, C1) * fmaf(2.f, sigco, C2);
        float den = (uu.x + uu.y + C1) * (sig.x + sig.y + C2);
        float q = num * __builtin_amdgcn_rcpf(den);
        float v = fminf(fmaxf(fmaf(q, -0.5f, 0.5f), 0.f), 1.f);
        if (j < 4) lo[j] = v; else hi[j - 4] = v;
    }
    // Regular cached stores: the two half-line-stride writes merge in L2,
    // so TCC->HBM WRITE_SIZE stays at the ideal 74 MB (NT bypassed the merge).
    float* o = out + base + (size_t)row * IMG_W + col0;
    *(v4f*)o       = lo;
    *(v4f*)(o + 4) = hi;
}

__global__ __launch_bounds__(64 * TY) void ssim_kernel(
    const float* __restrict__ pred,
    const float* __restrict__ target,
    float* __restrict__ out)
{
    const int lane = threadIdx.x;            // 0..63, one wave spans the full width
    const int col0 = 8 * lane;
    const size_t base = (size_t)blockIdx.z * (IMG_H * IMG_W);
    const int y0 = (blockIdx.y * TY + threadIdx.y) * RPT;

    Raw8 ra, rb, rc;
    H8 hA, hB, hC;

    // prologue: rows y0-1, y0, y0+1 (12 loads in flight)
    ISSUE(ra, y0 - 1); ISSUE(rb, y0); ISSUE(rc, y0 + 1);
    WAITV(8); hA = hrow(ra, lane);
    WAITV(4); hB = hrow(rb, lane);

    // steady state: issue row r+2, consume row r+1 (2 rows = 8 fat loads in flight)
    ISSUE(ra, y0 + 2); WAITV(4); hC = hrow(rc, lane);
    emit_row(out, base, y0 + 0, col0, hA, hB, hC);
    ISSUE(rb, y0 + 3); WAITV(4); hA = hrow(ra, lane);
    emit_row(out, base, y0 + 1, col0, hB, hC, hA);
    ISSUE(rc, y0 + 4); WAITV(4); hB = hrow(rb, lane);
    emit_row(out, base, y0 + 2, col0, hC, hA, hB);
    ISSUE(ra, y0 + 5); WAITV(4); hC = hrow(rc, lane);
    emit_row(out, base, y0 + 3, col0, hA, hB, hC);
    ISSUE(rb, y0 + 6); WAITV(4); hA = hrow(ra, lane);
    emit_row(out, base, y0 + 4, col0, hB, hC, hA);
    ISSUE(rc, y0 + 7); WAITV(4); hB = hrow(rb, lane);
    emit_row(out, base, y0 + 5, col0, hC, hA, hB);
    ISSUE(ra, y0 + 8); WAITV(4); hC = hrow(rc, lane);
    emit_row(out, base, y0 + 6, col0, hA, hB, hC);
    /* tail */         WAITV(0); hA = hrow(ra, lane);
    emit_row(out, base, y0 + 7, col0, hB, hC, hA);
}

extern "C" void kernel_launch(void* const* d_in, const int* in_sizes, int n_in,
                              void* d_out, int out_size, void* d_ws, size_t ws_size,
                              hipStream_t stream) {
    const float* pred   = (const float*)d_in[0];
    const float* target = (const float*)d_in[1];
    float* out = (float*)d_out;

    const int planes = in_sizes[0] / (IMG_H * IMG_W);   // 32*3 = 96

    dim3 block(64, TY);                                  // 256 threads = 4 waves
    dim3 grid(1, IMG_H / (TY * RPT), planes);            // (1, 12, 96)
    ssim_kernel<<<grid, block, 0, stream>>>(pred, target, out);
}

// Round 13
// 42.689 us; speedup vs baseline: 1.8508x; 1.1252x over previous
//
#include <hip/hip_runtime.h>

typedef float v2f __attribute__((ext_vector_type(2)));
typedef float v4f __attribute__((ext_vector_type(4)));

#define IMG_H 384
#define IMG_W 512
#define RPT 16          // output rows per thread (halo 18/16 = 1.125x)
#define TY  2           // strips per block
#define NLX 128         // lanes across x (128 * 4 cols = 512)

struct Raw  { v4f p, t; float pe, te; };
struct RowH { v2f hx[4]; v2f hxx[4]; float hpt[4]; };

__device__ __forceinline__ int reflect_y(int gy) {
    if (gy < 0) gy = -gy;
    else if (gy >= IMG_H) gy = 2 * IMG_H - 2 - gy;
    return gy;
}

// Issue one row's loads into ring slot S. Volatile asm: cannot be sunk/collapsed.
#define ISSUE(S, RY) do {                                                          \
    int gy_ = reflect_y(RY);                                                       \
    const float* rp_ = pred   + base + (size_t)gy_ * IMG_W;                        \
    const float* rt_ = target + base + (size_t)gy_ * IMG_W;                        \
    asm volatile("global_load_dwordx4 %0, %1, off" : "=v"(raw##S.p)  : "v"(rp_ + col0)); \
    asm volatile("global_load_dwordx4 %0, %1, off" : "=v"(raw##S.t)  : "v"(rt_ + col0)); \
    asm volatile("global_load_dword %0, %1, off"   : "=v"(raw##S.pe) : "v"(rp_ + eoff)); \
    asm volatile("global_load_dword %0, %1, off"   : "=v"(raw##S.te) : "v"(rt_ + eoff)); \
} while (0)

// Counted wait + scheduling fence (rule #18: fence AFTER the waitcnt).
#define WAITV(N) do {                                                              \
    asm volatile("s_waitcnt vmcnt(" #N ")" ::: "memory");                          \
    __builtin_amdgcn_sched_barrier(0);                                             \
} while (0)

__device__ __forceinline__ RowH reduce_row(const Raw& r, int lane, int col0)
{
    // window cols 4lx-1 .. 4lx+4; edges from neighbor lanes via shuffle
    float x0p = __shfl_up(r.p.w, 1);
    float x0t = __shfl_up(r.t.w, 1);
    float x5p = __shfl_down(r.p.x, 1);
    float x5t = __shfl_down(r.t.x, 1);
    if (lane == 0) {
        if (col0 == 0) { x0p = r.p.y; x0t = r.t.y; }      // reflect col -1 -> 1
        else           { x0p = r.pe;  x0t = r.te;  }      // cross-wave boundary
    }
    if (lane == 63) {
        if (col0 + 4 == IMG_W) { x5p = r.p.z; x5t = r.t.z; }  // reflect col W -> W-2
        else                   { x5p = r.pe;  x5t = r.te;  }  // cross-wave boundary
    }

    v2f x0 = {x0p,   x0t};
    v2f x1 = {r.p.x, r.t.x};
    v2f x2 = {r.p.y, r.t.y};
    v2f x3 = {r.p.z, r.t.z};
    v2f x4 = {r.p.w, r.t.w};
    v2f x5 = {x5p,   x5t};

    RowH h;
    v2f a = x1 + x2, b = x3 + x4;
    h.hx[0] = x0 + a;  h.hx[1] = a + x3;
    h.hx[2] = x2 + b;  h.hx[3] = b + x5;

    v2f q0 = x0*x0, q1 = x1*x1, q2 = x2*x2, q3 = x3*x3, q4 = x4*x4, q5 = x5*x5;
    v2f aq = q1 + q2, bq = q3 + q4;
    h.hxx[0] = q0 + aq;  h.hxx[1] = aq + q3;
    h.hxx[2] = q2 + bq;  h.hxx[3] = bq + q5;

    float m0 = x0.x*x0.y, m1 = x1.x*x1.y, m2 = x2.x*x2.y,
          m3 = x3.x*x3.y, m4 = x4.x*x4.y, m5 = x5.x*x5.y;
    float am = m1 + m2, bm = m3 + m4;
    h.hpt[0] = m0 + am;  h.hpt[1] = am + m3;
    h.hpt[2] = m2 + bm;  h.hpt[3] = bm + m5;
    return h;
}

__device__ __forceinline__ void emit_row(
    float* __restrict__ out, size_t base, int row, int col0,
    const RowH& A, const RowH& B, const RowH& C)
{
    const float C1 = 1e-4f;    // 0.01^2
    const float C2 = 9e-4f;    // 0.03^2
    const float inv9 = 1.0f / 9.0f;

    v4f rv;
    #pragma unroll
    for (int j = 0; j < 4; ++j) {
        v2f sx  = A.hx[j]  + B.hx[j]  + C.hx[j];
        v2f sxx = A.hxx[j] + B.hxx[j] + C.hxx[j];
        float spt = A.hpt[j] + B.hpt[j] + C.hpt[j];

        v2f u  = sx * inv9;
        v2f uu = u * u;
        v2f sig = sxx * inv9 - uu;
        float upt   = u.x * u.y;
        float sigco = fmaf(spt, inv9, -upt);

        float num = fmaf(2.f, upt, C1) * fmaf(2.f, sigco, C2);
        float den = (uu.x + uu.y + C1) * (sig.x + sig.y + C2);
        float q = num * __builtin_amdgcn_rcpf(den);
        rv[j] = fminf(fmaxf(fmaf(q, -0.5f, 0.5f), 0.f), 1.f);
    }
    __builtin_nontemporal_store(rv, (v4f*)(out + base + (size_t)row * IMG_W + col0));
}

__global__ __launch_bounds__(NLX * TY) void ssim_kernel(
    const float* __restrict__ pred,
    const float* __restrict__ target,
    float* __restrict__ out)
{
    const int lx   = threadIdx.x;            // 0..127
    const int lane = lx & 63;
    const int col0 = 4 * lx;
    const size_t base = (size_t)blockIdx.z * (IMG_H * IMG_W);
    const int y0 = (blockIdx.y * TY + threadIdx.y) * RPT;

    const bool needL = (lane == 0)  && (col0 != 0);
    const bool needR = (lane == 63) && (col0 + 4 != IMG_W);
    const int  eoff  = needL ? (col0 - 1) : (needR ? (col0 + 4) : col0); // interior: self-line (free)

    Raw raw0, raw1, raw2, raw3;
    RowH h0, h1, h2;

    // prologue: rows y0-1 .. y0+2 (16 loads in flight)
    ISSUE(0, y0 - 1); ISSUE(1, y0); ISSUE(2, y0 + 1); ISSUE(3, y0 + 2);
    WAITV(12); h0 = reduce_row(raw0, lane, col0);
    WAITV(8);  h1 = reduce_row(raw1, lane, col0);

    // steady state (16 steps): issue row r+3, consume row r+1 (8 loads in flight)
    ISSUE(0, y0 + 3);  WAITV(8); h2 = reduce_row(raw2, lane, col0);
    emit_row(out, base, y0 + 0,  col0, h0, h1, h2);
    ISSUE(1, y0 + 4);  WAITV(8); h0 = reduce_row(raw3, lane, col0);
    emit_row(out, base, y0 + 1,  col0, h1, h2, h0);
    ISSUE(2, y0 + 5);  WAITV(8); h1 = reduce_row(raw0, lane, col0);
    emit_row(out, base, y0 + 2,  col0, h2, h0, h1);
    ISSUE(3, y0 + 6);  WAITV(8); h2 = reduce_row(raw1, lane, col0);
    emit_row(out, base, y0 + 3,  col0, h0, h1, h2);
    ISSUE(0, y0 + 7);  WAITV(8); h0 = reduce_row(raw2, lane, col0);
    emit_row(out, base, y0 + 4,  col0, h1, h2, h0);
    ISSUE(1, y0 + 8);  WAITV(8); h1 = reduce_row(raw3, lane, col0);
    emit_row(out, base, y0 + 5,  col0, h2, h0, h1);
    ISSUE(2, y0 + 9);  WAITV(8); h2 = reduce_row(raw0, lane, col0);
    emit_row(out, base, y0 + 6,  col0, h0, h1, h2);
    ISSUE(3, y0 + 10); WAITV(8); h0 = reduce_row(raw1, lane, col0);
    emit_row(out, base, y0 + 7,  col0, h1, h2, h0);
    ISSUE(0, y0 + 11); WAITV(8); h1 = reduce_row(raw2, lane, col0);
    emit_row(out, base, y0 + 8,  col0, h2, h0, h1);
    ISSUE(1, y0 + 12); WAITV(8); h2 = reduce_row(raw3, lane, col0);
    emit_row(out, base, y0 + 9,  col0, h0, h1, h2);
    ISSUE(2, y0 + 13); WAITV(8); h0 = reduce_row(raw0, lane, col0);
    emit_row(out, base, y0 + 10, col0, h1, h2, h0);
    ISSUE(3, y0 + 14); WAITV(8); h1 = reduce_row(raw1, lane, col0);
    emit_row(out, base, y0 + 11, col0, h2, h0, h1);
    ISSUE(0, y0 + 15); WAITV(8); h2 = reduce_row(raw2, lane, col0);
    emit_row(out, base, y0 + 12, col0, h0, h1, h2);
    ISSUE(1, y0 + 16); WAITV(8); h0 = reduce_row(raw3, lane, col0);
    emit_row(out, base, y0 + 13, col0, h1, h2, h0);
    /* tail */         WAITV(4); h1 = reduce_row(raw0, lane, col0);
    emit_row(out, base, y0 + 14, col0, h2, h0, h1);
                       WAITV(0); h2 = reduce_row(raw1, lane, col0);
    emit_row(out, base, y0 + 15, col0, h0, h1, h2);
}

extern "C" void kernel_launch(void* const* d_in, const int* in_sizes, int n_in,
                              void* d_out, int out_size, void* d_ws, size_t ws_size,
                              hipStream_t stream) {
    const float* pred   = (const float*)d_in[0];
    const float* target = (const float*)d_in[1];
    float* out = (float*)d_out;

    const int planes = in_sizes[0] / (IMG_H * IMG_W);   // 32*3 = 96

    dim3 block(NLX, TY);                                 // 256 threads
    dim3 grid(1, IMG_H / (TY * RPT), planes);            // (1, 12, 96)
    ssim_kernel<<<grid, block, 0, stream>>>(pred, target, out);
}